// Round 1
// 3098.045 us; speedup vs baseline: 1.0134x; 1.0134x over previous
//
#include <hip/hip_runtime.h>

#define BB   64
#define PP   196
#define ENC  2048
#define AA   512
#define EE   512
#define DD   512
#define VV   20000
#define TT   21
#define ML   22

#define PRED_ELEMS ((size_t)BB * TT * VV)   // 26,880,000

typedef __attribute__((ext_vector_type(8))) short s8bf;    // 8 bf16 (4 VGPRs)
typedef __attribute__((ext_vector_type(4))) float f4acc;   // 4 fp32 acc

__device__ __forceinline__ float bf2f(unsigned short u) {
    union { unsigned int i; float f; } v; v.i = ((unsigned int)u) << 16; return v.f;
}
__device__ __forceinline__ void unpack2(unsigned int u, float& lo, float& hi) {
    union { unsigned int i; float f; } a, b;
    a.i = u << 16; b.i = u & 0xFFFF0000u; lo = a.f; hi = b.f;
}
__device__ __forceinline__ unsigned short f2bf(float f) {
    union { float f; unsigned int i; } v; v.f = f;
    unsigned int i = v.i;
    return (unsigned short)((i + 0x7FFFu + ((i >> 16) & 1u)) >> 16); // RNE
}
__device__ __forceinline__ float sigmoidf(float x) { return 1.0f / (1.0f + __expf(-x)); }

template <bool F> __device__ __forceinline__ float ldw(const void* p, size_t i) {
    if (F) return ((const float*)p)[i];
    return bf2f(((const unsigned short*)p)[i]);
}
template <bool F> __device__ __forceinline__ unsigned short ldbf(const void* p, size_t i) {
    if (F) return f2bf(((const float*)p)[i]);   // exact: values are bf16-quantized
    return ((const unsigned short*)p)[i];
}
template <bool F> __device__ __forceinline__ float2 ld2(const void* p, size_t i) {
    if (F) return *(const float2*)((const float*)p + i);
    unsigned int u = *(const unsigned int*)((const unsigned short*)p + i);
    float lo, hi; unpack2(u, lo, hi); return make_float2(lo, hi);
}
template <bool F> __device__ __forceinline__ float4 ld4(const void* p, size_t i) {
    if (F) return *(const float4*)((const float*)p + i);
    uint2 u = *(const uint2*)((const unsigned short*)p + i);
    float a, b, c, d; unpack2(u.x, a, b); unpack2(u.y, c, d);
    return make_float4(a, b, c, d);
}
template <bool F> __device__ __forceinline__ void st1(void* p, size_t i, float v) {
    if (F) ((float*)p)[i] = v; else ((unsigned short*)p)[i] = f2bf(v);
}

// ---------------- dtype detector ----------------
__global__ void dec_detect_kernel(const unsigned short* __restrict__ enc_us, int* __restrict__ flag) {
    __shared__ int s_cnt;
    if (threadIdx.x == 0) s_cnt = 0;
    __syncthreads();
    int cnt = 0;
    for (int i = threadIdx.x; i < 8192; i += 256) {
        unsigned short u = enc_us[2 * i];
        if ((u & 0x7F80) == 0x7F80) cnt++;
    }
    if (cnt) atomicAdd(&s_cnt, cnt);
    __syncthreads();
    if (threadIdx.x == 0) *flag = (s_cnt > 0) ? 1 : 0;
}

// ---------------- weight swizzle: W[K x N] -> bf16 [nt][kc][lane][8] ----------------
// B-fragment for mfma_16x16x32: lane=(quad*16+l15), element j -> W[kc*32+quad*8+j][nt*16+l15]
// permMode 1: LSTM gate interleave (16-wide): n' -> orig col = gate*512 + dchunk*16 + dl
//   gate=(np>>4)&3, dchunk=np>>6, dl=np&15  -> each 64-col block = 4 gates x 16 d's
template <bool F>
__device__ __forceinline__ void conv_swz_body(const void* W, int K, int Norig,
                                              unsigned short* dst, int permMode, int nChunks) {
    int chunk = blockIdx.x * 4 + (threadIdx.x >> 6);
    if (chunk >= nChunks) return;
    int lane = threadIdx.x & 63;
    int KC = K >> 5;
    int nt = chunk / KC, kc = chunk % KC;
    int quad = lane >> 4, l15 = lane & 15;
    int np = nt * 16 + l15;
    int col;
    if (permMode == 1) col = ((np >> 4) & 3) * 512 + (np >> 6) * 16 + (np & 15);
    else col = np;
    union { s8bf v; unsigned short s[8]; } o;
    if (np < Norig || permMode == 1) {
        size_t base = (size_t)(kc * 32 + quad * 8) * Norig + col;
#pragma unroll
        for (int j = 0; j < 8; ++j) o.s[j] = ldbf<F>(W, base + (size_t)j * Norig);
    } else {
#pragma unroll
        for (int j = 0; j < 8; ++j) o.s[j] = 0;
    }
    *(s8bf*)(dst + ((size_t)chunk * 64 + lane) * 8) = o.v;
}
__global__ void conv_swz_kernel(const int* __restrict__ flg, const void* __restrict__ W,
                                int K, int Norig, unsigned short* __restrict__ dst,
                                int permMode, int nChunks) {
    if (*flg) conv_swz_body<true>(W, K, Norig, dst, permMode, nChunks);
    else      conv_swz_body<false>(W, K, Norig, dst, permMode, nChunks);
}

// ---------------- bias prep (all epilogue biases as f32) ----------------
template <bool F>
__device__ __forceinline__ void conv_bias_body(const void* dab, const void* fbb,
                                               const void* bih, const void* bhh, const void* fcb,
                                               const void* ihb, const void* icb, const void* eab,
                                               float* ag_b, float* g_b, float* fc_b,
                                               float* ihb_f, float* icb_f, float* eab_f) {
    int i = blockIdx.x * 256 + threadIdx.x;
    if (i < 2560) ag_b[i] = (i < 512) ? ldw<F>(dab, i) : ldw<F>(fbb, i - 512);
    else if (i < 2560 + 2048) {
        int np = i - 2560;
        int orig = ((np >> 4) & 3) * 512 + (np >> 6) * 16 + (np & 15);
        g_b[np] = ldw<F>(bih, orig) + ldw<F>(bhh, orig);
    } else if (i < 2560 + 2048 + 20000) fc_b[i - 4608] = ldw<F>(fcb, i - 4608);
    else if (i < 2560 + 2048 + 20000 + 512) ihb_f[i - 24608] = ldw<F>(ihb, i - 24608);
    else if (i < 2560 + 2048 + 20000 + 1024) icb_f[i - 25120] = ldw<F>(icb, i - 25120);
    else if (i < 2560 + 2048 + 20000 + 1536) eab_f[i - 25632] = ldw<F>(eab, i - 25632);
}
__global__ void conv_bias_kernel(const int* __restrict__ flg,
                                 const void* dab, const void* fbb, const void* bih, const void* bhh,
                                 const void* fcb, const void* ihb, const void* icb, const void* eab,
                                 float* ag_b, float* g_b, float* fc_b,
                                 float* ihb_f, float* icb_f, float* eab_f) {
    if (*flg) conv_bias_body<true>(dab, fbb, bih, bhh, fcb, ihb, icb, eab, ag_b, g_b, fc_b, ihb_f, icb_f, eab_f);
    else      conv_bias_body<false>(dab, fbb, bih, bhh, fcb, ihb, icb, eab, ag_b, g_b, fc_b, ihb_f, icb_f, eab_f);
}

// ---------------- mean over P -> bf16 ----------------
template <bool F>
__device__ __forceinline__ void mean_body(const void* enc, unsigned short* mean_bf) {
    int b = blockIdx.x;
    int e = blockIdx.y * 256 + threadIdx.x;
    size_t base = (size_t)b * PP * ENC + e;
    float s = 0.f;
#pragma unroll 4
    for (int p = 0; p < PP; ++p) s += ldw<F>(enc, base + (size_t)p * ENC);
    mean_bf[b * ENC + e] = f2bf(s * (1.0f / (float)PP));
}
__global__ void dec_mean_kernel(const void* __restrict__ enc, const int* __restrict__ flg,
                                unsigned short* __restrict__ mean_bf) {
    if (*flg) mean_body<true>(enc, mean_bf); else mean_body<false>(enc, mean_bf);
}

// ---------------- unified M=64 MFMA GEMM, swizzled-B, fused epilogues ----------------
// nct = N-tiles(64) per block: block covers 64*nct columns at blockIdx.y.
// epi 0: outF[m*N+n] = v                   (c0)
// epi 1: n<512 -> att2f[m*512+n]=v ; else gatef[m*2048+n-512]=sigmoid(v)
// epi 2: BATCHED preds: blockIdx.x = t, A1 = h_all (rows t*64..t*64+63); masked write to outV
// epi 3: hb[m*512+n] = bf16(v)             (h0)
// epi 4: gates (16-wide perm cols) + fused LSTM: c update, hb=h_out (ping-pong), h_all[t]
__global__ __launch_bounds__(256)
void gemm_u_kernel(const int* __restrict__ flg,
                   const unsigned short* __restrict__ A1, int K1, const unsigned short* __restrict__ W1,
                   const unsigned short* __restrict__ A2, int K2, const unsigned short* __restrict__ W2,
                   const float* __restrict__ bias, int N, int epi, int nct,
                   float* __restrict__ outF, float* __restrict__ outF2,
                   unsigned short* __restrict__ hb, float* __restrict__ cptr,
                   unsigned short* __restrict__ h_all,
                   void* __restrict__ outV, const int* __restrict__ lengths, int t) {
    __shared__ float s_g[4 * 64 * 17];                 // padded stride 17: bank-spread
    int tid = threadIdx.x;
    int wave = tid >> 6, lane = tid & 63;
    int l15 = lane & 15, quad = lane >> 4;
    const unsigned short* Abase1 = A1;
    if (epi == 2) Abase1 = A1 + (size_t)blockIdx.x * 64 * K1;   // t-th M-tile of h_all
    f4acc acc[4][2];
#pragma unroll
    for (int a = 0; a < 4; ++a) { acc[a][0] = (f4acc)0.f; acc[a][1] = (f4acc)0.f; }
#pragma unroll
    for (int pass = 0; pass < 2; ++pass) {
        const unsigned short* A = pass ? A2 : Abase1;
        if (!A) continue;
        int K = pass ? K2 : K1;
        const unsigned short* W = pass ? W2 : W1;
        int KC = K >> 5;
        for (int kc = 0; kc < KC; ++kc) {
            s8bf af[4];
#pragma unroll
            for (int rt = 0; rt < 4; ++rt)
                af[rt] = *(const s8bf*)(A + (size_t)(rt * 16 + l15) * K + kc * 32 + quad * 8);
#pragma unroll
            for (int ct = 0; ct < 2; ++ct) if (ct < nct) {
                int nt = blockIdx.y * 4 * nct + ct * 4 + wave;
                s8bf bv = *(const s8bf*)(W + ((size_t)(nt * KC + kc) * 64 + lane) * 8);
#pragma unroll
                for (int rt = 0; rt < 4; ++rt)
                    acc[rt][ct] = __builtin_amdgcn_mfma_f32_16x16x32_bf16(af[rt], bv, acc[rt][ct], 0, 0, 0);
            }
        }
    }
    if (epi == 4) {
        // nct==1: block covers cols np = blockIdx.y*64 + nl, nl = wave*16+l15
        // gate g=(nl>>4)&3, dl=nl&15 ; d = blockIdx.y*16 + dl
        int nl = wave * 16 + l15;
        int g = (nl >> 4) & 3, dl = nl & 15;
        float bv = bias[blockIdx.y * 64 + nl];
#pragma unroll
        for (int rt = 0; rt < 4; ++rt)
#pragma unroll
            for (int r = 0; r < 4; ++r) {
                int m = rt * 16 + quad * 4 + r;
                s_g[(g * 64 + m) * 17 + dl] = acc[rt][0][r] + bv;
            }
        __syncthreads();
        int m = tid >> 2;
        bool act = t < (lengths[m] - 1);
#pragma unroll
        for (int i = 0; i < 4; ++i) {
            int dl2 = (tid & 3) * 4 + i;
            int d = blockIdx.y * 16 + dl2;
            unsigned short hv;
            if (act) {
                float ig = sigmoidf(s_g[(0 * 64 + m) * 17 + dl2]);
                float fg = sigmoidf(s_g[(1 * 64 + m) * 17 + dl2]);
                float gg = tanhf(s_g[(2 * 64 + m) * 17 + dl2]);
                float og = sigmoidf(s_g[(3 * 64 + m) * 17 + dl2]);
                float cn = fg * cptr[m * DD + d] + ig * gg;
                float hn = og * tanhf(cn);
                cptr[m * DD + d] = cn;
                hv = f2bf(hn);
            } else {
                hv = A2[(size_t)m * K2 + d];     // carry old h forward (ping-pong copy)
            }
            hb[m * DD + d] = hv;
            h_all[((size_t)t * BB + m) * DD + d] = hv;
        }
        return;
    }
    bool f32o = (epi == 2) ? (*flg != 0) : false;
    int tb = blockIdx.x;
#pragma unroll
    for (int ct = 0; ct < 2; ++ct) if (ct < nct) {
        int n = blockIdx.y * 64 * nct + ct * 64 + wave * 16 + l15;
        if (n >= N) continue;
        float bv = bias ? bias[n] : 0.f;
#pragma unroll
        for (int rt = 0; rt < 4; ++rt)
#pragma unroll
            for (int r = 0; r < 4; ++r) {
                int m = rt * 16 + quad * 4 + r;
                float v = acc[rt][ct][r] + bv;
                if (epi == 0)      outF[(size_t)m * N + n] = v;
                else if (epi == 1) {
                    if (n < 512) outF[(size_t)m * 512 + n] = v;
                    else         outF2[(size_t)m * 2048 + (n - 512)] = sigmoidf(v);
                } else if (epi == 3) hb[(size_t)m * DD + n] = f2bf(v);
                else {             // epi 2: batched preds, t = blockIdx.x
                    bool act = tb < (lengths[m] - 1);
                    float pv = act ? v : 0.f;
                    size_t oi = ((size_t)m * TT + tb) * VV + n;
                    if (f32o) ((float*)outV)[oi] = pv; else ((unsigned short*)outV)[oi] = f2bf(pv);
                }
            }
    }
}

// ---------------- att1: MFMA GEMM (M=12544, N=512, K=2048), swizzled B ----------------
template <bool F>
__device__ __forceinline__ void att1_gemm_body(const void* enc, const unsigned short* Wsw,
                                               const float* bias, float* att1) {
    __shared__ __attribute__((aligned(16))) unsigned short As[64 * 40];
    int tid = threadIdx.x;
    int wave = tid >> 6, lane = tid & 63;
    int l15 = lane & 15, quad = lane >> 4;
    int row0 = blockIdx.x * 64;
    f4acc acc[4][2];
#pragma unroll
    for (int a = 0; a < 4; ++a) { acc[a][0] = (f4acc)0.f; acc[a][1] = (f4acc)0.f; }
    int lr = tid >> 2, lk = (tid & 3) * 8;
    for (int kc = 0; kc < 64; ++kc) {
        int k0 = kc * 32;
        if (F) {
            const float* src = (const float*)enc + (size_t)(row0 + lr) * ENC + k0 + lk;
            float4 v0 = *(const float4*)src, v1 = *(const float4*)(src + 4);
            union { s8bf v; unsigned short s[8]; } t8;
            t8.s[0]=f2bf(v0.x); t8.s[1]=f2bf(v0.y); t8.s[2]=f2bf(v0.z); t8.s[3]=f2bf(v0.w);
            t8.s[4]=f2bf(v1.x); t8.s[5]=f2bf(v1.y); t8.s[6]=f2bf(v1.z); t8.s[7]=f2bf(v1.w);
            *(s8bf*)&As[lr * 40 + lk] = t8.v;
        } else {
            *(s8bf*)&As[lr * 40 + lk] =
                *(const s8bf*)((const unsigned short*)enc + (size_t)(row0 + lr) * ENC + k0 + lk);
        }
        __syncthreads();
        s8bf af[4];
#pragma unroll
        for (int rt = 0; rt < 4; ++rt)
            af[rt] = *(const s8bf*)&As[(rt * 16 + l15) * 40 + quad * 8];
#pragma unroll
        for (int ct = 0; ct < 2; ++ct) {
            int nt = blockIdx.y * 8 + ct * 4 + wave;
            s8bf bv = *(const s8bf*)(Wsw + ((size_t)(nt * 64 + kc) * 64 + lane) * 8);
#pragma unroll
            for (int rt = 0; rt < 4; ++rt)
                acc[rt][ct] = __builtin_amdgcn_mfma_f32_16x16x32_bf16(af[rt], bv, acc[rt][ct], 0, 0, 0);
        }
        __syncthreads();
    }
#pragma unroll
    for (int ct = 0; ct < 2; ++ct) {
        int n = blockIdx.y * 128 + ct * 64 + wave * 16 + l15;
        float bv = bias[n];
#pragma unroll
        for (int rt = 0; rt < 4; ++rt)
#pragma unroll
            for (int r = 0; r < 4; ++r) {
                int m = row0 + rt * 16 + quad * 4 + r;
                att1[(size_t)m * AA + n] = acc[rt][ct][r] + bv;
            }
    }
}
__global__ __launch_bounds__(256)
void gemm_att1_kernel(const void* __restrict__ enc, const int* __restrict__ flg,
                      const unsigned short* __restrict__ Wsw, const float* __restrict__ bias,
                      float* __restrict__ att1) {
    if (*flg) att1_gemm_body<true>(enc, Wsw, bias, att1);
    else      att1_gemm_body<false>(enc, Wsw, bias, att1);
}

// ---------------- scores + softmax (wave-per-row, coalesced, reg-resident att2/fw) ----------------
template <bool F>
__device__ __forceinline__ void att_body(const float* att1, const float* att2,
                                         const void* faw, const void* fab,
                                         const int* lengths, float* alpha_ws, void* out, int t) {
    __shared__ float s_sc[256];
    __shared__ float s_red[256];
    int b = blockIdx.x, tid = threadIdx.x;
    int wave = tid >> 6, lane = tid & 63;
    int a0i = lane * 8;
    float4 a2a = *(const float4*)(att2 + (size_t)b * AA + a0i);
    float4 a2b = *(const float4*)(att2 + (size_t)b * AA + a0i + 4);
    float4 w0 = ld4<F>(faw, a0i);
    float4 w1 = ld4<F>(faw, a0i + 4);
    float fabv = ldw<F>(fab, 0);
    s_sc[tid] = -1e30f;
    __syncthreads();
#pragma unroll 2
    for (int r = wave; r < PP; r += 4) {
        const float4* row = (const float4*)(att1 + ((size_t)b * PP + r) * AA);
        float4 v0 = row[lane * 2];
        float4 v1 = row[lane * 2 + 1];
        float acc = fmaxf(v0.x + a2a.x, 0.f) * w0.x
                  + fmaxf(v0.y + a2a.y, 0.f) * w0.y
                  + fmaxf(v0.z + a2a.z, 0.f) * w0.z
                  + fmaxf(v0.w + a2a.w, 0.f) * w0.w
                  + fmaxf(v1.x + a2b.x, 0.f) * w1.x
                  + fmaxf(v1.y + a2b.y, 0.f) * w1.y
                  + fmaxf(v1.z + a2b.z, 0.f) * w1.z
                  + fmaxf(v1.w + a2b.w, 0.f) * w1.w;
#pragma unroll
        for (int off = 32; off; off >>= 1) acc += __shfl_xor(acc, off, 64);
        if (lane == 0) s_sc[r] = acc + fabv;
    }
    __syncthreads();
    float sc = s_sc[tid];
    s_red[tid] = sc;
    __syncthreads();
    for (int s = 128; s > 0; s >>= 1) { if (tid < s) s_red[tid] = fmaxf(s_red[tid], s_red[tid + s]); __syncthreads(); }
    float m = s_red[0];
    __syncthreads();
    float e = 0.f;
    if (tid < PP) e = __expf(sc - m);
    s_red[tid] = e;
    __syncthreads();
    for (int s = 128; s > 0; s >>= 1) { if (tid < s) s_red[tid] += s_red[tid + s]; __syncthreads(); }
    float inv = 1.0f / s_red[0];
    if (tid < PP) {
        float al = e * inv;
        alpha_ws[b * PP + tid] = al;
        bool active = t < (lengths[b] - 1);
        st1<F>(out, PRED_ELEMS + (size_t)(b * TT + t) * PP + tid, active ? al : 0.f);
    }
}
__global__ void dec_att_kernel(const float* __restrict__ att1, const float* __restrict__ att2,
                               const int* __restrict__ flg,
                               const void* __restrict__ faw, const void* __restrict__ fab,
                               const int* __restrict__ lengths,
                               float* __restrict__ alpha_ws, void* __restrict__ out, int t) {
    if (*flg) att_body<true>(att1, att2, faw, fab, lengths, alpha_ws, out, t);
    else      att_body<false>(att1, att2, faw, fab, lengths, alpha_ws, out, t);
}

// ---------------- fused context + gate + x_bf assembly ----------------
// grid (BB, 4), 256 thr; block (b,yc) handles 512 ctx dims (float2/thread); yc==0 also writes emb part
template <bool F>
__device__ __forceinline__ void ctx_body(const void* enc, const float* alpha_ws, const float* gate,
                                         const void* emb, const int* captions,
                                         unsigned short* x_bf, int t) {
    __shared__ float s_al[PP];
    int b = blockIdx.x, yc = blockIdx.y, tid = threadIdx.x;
    if (tid < PP) s_al[tid] = alpha_ws[b * PP + tid];
    __syncthreads();
    if (yc == 0) {
        int cap = captions[b * ML + t];
        int i = tid * 2;
        float2 ev = ld2<F>(emb, (size_t)cap * EE + i);
        *(unsigned int*)(x_bf + (size_t)b * 2560 + i) =
            (unsigned int)f2bf(ev.x) | ((unsigned int)f2bf(ev.y) << 16);
    }
    int e = yc * 512 + tid * 2;
    float a0 = 0.f, a1 = 0.f;
    size_t base = (size_t)b * PP * ENC + e;
#pragma unroll 4
    for (int p = 0; p < PP; ++p) {
        float al = s_al[p];
        float2 v = ld2<F>(enc, base + (size_t)p * ENC);
        a0 += al * v.x; a1 += al * v.y;
    }
    float2 g = *(const float2*)&gate[(size_t)b * ENC + e];
    *(unsigned int*)(x_bf + (size_t)b * 2560 + EE + e) =
        (unsigned int)f2bf(a0 * g.x) | ((unsigned int)f2bf(a1 * g.y) << 16);
}
__global__ void dec_ctx_kernel(const void* __restrict__ enc, const int* __restrict__ flg,
                               const float* __restrict__ alpha_ws, const float* __restrict__ gate,
                               const void* __restrict__ emb, const int* __restrict__ captions,
                               unsigned short* __restrict__ x_bf, int t) {
    if (*flg) ctx_body<true>(enc, alpha_ws, gate, emb, captions, x_bf, t);
    else      ctx_body<false>(enc, alpha_ws, gate, emb, captions, x_bf, t);
}

extern "C" void kernel_launch(void* const* d_in, const int* in_sizes, int n_in,
                              void* d_out, int out_size, void* d_ws, size_t ws_size,
                              hipStream_t stream) {
    const void* enc      = d_in[0];
    const int* captions  = (const int*)d_in[1];
    const int* lengths   = (const int*)d_in[2];
    const void* emb      = d_in[3];
    const void* eaw      = d_in[4];
    const void* eab      = d_in[5];
    const void* daw      = d_in[6];
    const void* dab      = d_in[7];
    const void* faw      = d_in[8];
    const void* fab      = d_in[9];
    const void* wih      = d_in[10];
    const void* bih      = d_in[11];
    const void* whh      = d_in[12];
    const void* bhh      = d_in[13];
    const void* ihw      = d_in[14];
    const void* ihb      = d_in[15];
    const void* icw      = d_in[16];
    const void* icb      = d_in[17];
    const void* fbw      = d_in[18];
    const void* fbb      = d_in[19];
    const void* fcw      = d_in[20];
    const void* fcb      = d_in[21];

    char* cur = (char*)d_ws;
    auto alloc = [&](size_t bytes) { void* p = cur; cur += (bytes + 255) & ~(size_t)255; return p; };
    int* flg               = (int*)alloc(4);
    unsigned short* h_bufA = (unsigned short*)alloc((size_t)BB * DD * 2);
    unsigned short* h_bufB = (unsigned short*)alloc((size_t)BB * DD * 2);
    unsigned short* h_all  = (unsigned short*)alloc((size_t)TT * BB * DD * 2);   // 1.4 MB
    unsigned short* x_bf   = (unsigned short*)alloc((size_t)BB * 2560 * 2);
    unsigned short* mean_bf= (unsigned short*)alloc((size_t)BB * ENC * 2);
    float* c               = (float*)alloc((size_t)BB * DD * 4);
    float* att2            = (float*)alloc((size_t)BB * AA * 4);
    float* gate            = (float*)alloc((size_t)BB * ENC * 4);
    float* alpha           = (float*)alloc((size_t)BB * PP * 4);
    float* ag_bias         = (float*)alloc(2560 * 4);
    float* g_bias          = (float*)alloc(2048 * 4);
    float* fc_bias         = (float*)alloc(20000 * 4);
    float* ihb_f           = (float*)alloc(512 * 4);
    float* icb_f           = (float*)alloc(512 * 4);
    float* eab_f           = (float*)alloc(512 * 4);
    unsigned short* eaw_sw = (unsigned short*)alloc((size_t)32 * 64 * 512 * 2);       // 2.1 MB
    unsigned short* ag_sw  = (unsigned short*)alloc((size_t)160 * 16 * 512 * 2);      // 2.6 MB
    unsigned short* ihw_sw = (unsigned short*)alloc((size_t)32 * 64 * 512 * 2);
    unsigned short* icw_sw = (unsigned short*)alloc((size_t)32 * 64 * 512 * 2);
    unsigned short* wih_sw = (unsigned short*)alloc((size_t)128 * 80 * 512 * 2);      // 10.5 MB
    unsigned short* whh_sw = (unsigned short*)alloc((size_t)128 * 16 * 512 * 2);      // 2.1 MB
    unsigned short* fcw_sw = (unsigned short*)alloc((size_t)1256 * 16 * 512 * 2);     // 20.6 MB
    float* att1            = (float*)alloc((size_t)BB * PP * AA * 4);                 // 25.7 MB

    dec_detect_kernel<<<1, 256, 0, stream>>>((const unsigned short*)enc, flg);
    conv_swz_kernel<<<(32 * 64 + 3) / 4, 256, 0, stream>>>(flg, eaw, ENC, AA, eaw_sw, 0, 32 * 64);
    conv_swz_kernel<<<(32 * 16 + 3) / 4, 256, 0, stream>>>(flg, daw, DD, AA, ag_sw, 0, 32 * 16);
    conv_swz_kernel<<<(128 * 16 + 3) / 4, 256, 0, stream>>>(flg, fbw, DD, ENC, ag_sw + (size_t)32 * 16 * 512, 0, 128 * 16);
    conv_swz_kernel<<<(32 * 64 + 3) / 4, 256, 0, stream>>>(flg, ihw, ENC, DD, ihw_sw, 0, 32 * 64);
    conv_swz_kernel<<<(32 * 64 + 3) / 4, 256, 0, stream>>>(flg, icw, ENC, DD, icw_sw, 0, 32 * 64);
    conv_swz_kernel<<<(128 * 80 + 3) / 4, 256, 0, stream>>>(flg, wih, 2560, 2048, wih_sw, 1, 128 * 80);
    conv_swz_kernel<<<(128 * 16 + 3) / 4, 256, 0, stream>>>(flg, whh, DD, 2048, whh_sw, 1, 128 * 16);
    conv_swz_kernel<<<(1256 * 16 + 3) / 4, 256, 0, stream>>>(flg, fcw, DD, VV, fcw_sw, 0, 1256 * 16);
    conv_bias_kernel<<<(26144 + 255) / 256, 256, 0, stream>>>(flg, dab, fbb, bih, bhh, fcb, ihb, icb, eab,
                                                              ag_bias, g_bias, fc_bias, ihb_f, icb_f, eab_f);
    dec_mean_kernel<<<dim3(BB, ENC / 256), 256, 0, stream>>>(enc, flg, mean_bf);
    // h0, c0 via MFMA
    gemm_u_kernel<<<dim3(1, 4), 256, 0, stream>>>(flg, mean_bf, ENC, ihw_sw, nullptr, 0, nullptr,
                                                  ihb_f, DD, 3, 2, nullptr, nullptr, h_bufA, nullptr,
                                                  nullptr, nullptr, nullptr, 0);
    gemm_u_kernel<<<dim3(1, 4), 256, 0, stream>>>(flg, mean_bf, ENC, icw_sw, nullptr, 0, nullptr,
                                                  icb_f, DD, 0, 2, c, nullptr, nullptr, nullptr,
                                                  nullptr, nullptr, nullptr, 0);
    gemm_att1_kernel<<<dim3(196, 4), 256, 0, stream>>>(enc, flg, eaw_sw, eab_f, att1);

    unsigned short* hcur = h_bufA;
    for (int t = 0; t < TT; ++t) {
        unsigned short* hnext = (hcur == h_bufA) ? h_bufB : h_bufA;
        // att2 (cols 0..511) + f_beta gate (cols 512..2559), fused; nct=1 -> 40 blocks
        gemm_u_kernel<<<dim3(1, 40), 256, 0, stream>>>(flg, hcur, DD, ag_sw, nullptr, 0, nullptr,
                                                       ag_bias, 2560, 1, 1, att2, gate, nullptr, nullptr,
                                                       nullptr, nullptr, nullptr, 0);
        dec_att_kernel<<<BB, 256, 0, stream>>>(att1, att2, flg, faw, fab, lengths, alpha, d_out, t);
        dec_ctx_kernel<<<dim3(BB, 4), 256, 0, stream>>>(enc, flg, alpha, gate, emb, captions, x_bf, t);
        // gates GEMM + fused LSTM pointwise (16-wide gate-interleaved cols); nct=1 -> 32 blocks
        gemm_u_kernel<<<dim3(1, 32), 256, 0, stream>>>(flg, x_bf, 2560, wih_sw, hcur, DD, whh_sw,
                                                       g_bias, 2048, 4, 1, nullptr, nullptr, hnext, c,
                                                       h_all, nullptr, lengths, t);
        hcur = hnext;
    }
    // batched vocab projection: M = TT*64, grid (t, n-tile) -> 3297 blocks
    gemm_u_kernel<<<dim3(TT, 157), 256, 0, stream>>>(flg, h_all, DD, fcw_sw, nullptr, 0, nullptr,
                                                     fc_bias, VV, 2, 2, nullptr, nullptr, nullptr, nullptr,
                                                     nullptr, d_out, lengths, 0);
}

// Round 3
// 2753.589 us; speedup vs baseline: 1.1402x; 1.1251x over previous
//
#include <hip/hip_runtime.h>

#define BB   64
#define PP   196
#define ENC  2048
#define AA   512
#define EE   512
#define DD   512
#define VV   20000
#define TT   21
#define ML   22

#define PRED_ELEMS ((size_t)BB * TT * VV)   // 26,880,000

typedef __attribute__((ext_vector_type(8))) short s8bf;    // 8 bf16 (4 VGPRs)
typedef __attribute__((ext_vector_type(4))) float f4acc;   // 4 fp32 acc

__device__ __forceinline__ float bf2f(unsigned short u) {
    union { unsigned int i; float f; } v; v.i = ((unsigned int)u) << 16; return v.f;
}
__device__ __forceinline__ void unpack2(unsigned int u, float& lo, float& hi) {
    union { unsigned int i; float f; } a, b;
    a.i = u << 16; b.i = u & 0xFFFF0000u; lo = a.f; hi = b.f;
}
__device__ __forceinline__ unsigned short f2bf(float f) {
    union { float f; unsigned int i; } v; v.f = f;
    unsigned int i = v.i;
    return (unsigned short)((i + 0x7FFFu + ((i >> 16) & 1u)) >> 16); // RNE
}
__device__ __forceinline__ float sigmoidf(float x) { return 1.0f / (1.0f + __expf(-x)); }

template <bool F> __device__ __forceinline__ float ldw(const void* p, size_t i) {
    if (F) return ((const float*)p)[i];
    return bf2f(((const unsigned short*)p)[i]);
}
template <bool F> __device__ __forceinline__ unsigned short ldbf(const void* p, size_t i) {
    if (F) return f2bf(((const float*)p)[i]);   // exact: values are bf16-quantized
    return ((const unsigned short*)p)[i];
}
template <bool F> __device__ __forceinline__ float2 ld2(const void* p, size_t i) {
    if (F) return *(const float2*)((const float*)p + i);
    unsigned int u = *(const unsigned int*)((const unsigned short*)p + i);
    float lo, hi; unpack2(u, lo, hi); return make_float2(lo, hi);
}
template <bool F> __device__ __forceinline__ float4 ld4(const void* p, size_t i) {
    if (F) return *(const float4*)((const float*)p + i);
    uint2 u = *(const uint2*)((const unsigned short*)p + i);
    float a, b, c, d; unpack2(u.x, a, b); unpack2(u.y, c, d);
    return make_float4(a, b, c, d);
}
template <bool F> __device__ __forceinline__ void st1(void* p, size_t i, float v) {
    if (F) ((float*)p)[i] = v; else ((unsigned short*)p)[i] = f2bf(v);
}

// ---------------- dtype detector ----------------
__global__ void dec_detect_kernel(const unsigned short* __restrict__ enc_us, int* __restrict__ flag) {
    __shared__ int s_cnt;
    if (threadIdx.x == 0) s_cnt = 0;
    __syncthreads();
    int cnt = 0;
    for (int i = threadIdx.x; i < 8192; i += 256) {
        unsigned short u = enc_us[2 * i];
        if ((u & 0x7F80) == 0x7F80) cnt++;
    }
    if (cnt) atomicAdd(&s_cnt, cnt);
    __syncthreads();
    if (threadIdx.x == 0) *flag = (s_cnt > 0) ? 1 : 0;
}

// ---------------- enc -> bf16 copy (once; only launched if workspace fits) ----------------
template <bool F>
__device__ __forceinline__ void encconv_body(const void* enc, unsigned short* dst) {
    size_t i = ((size_t)blockIdx.x * 256 + threadIdx.x) * 8;
    if (F) {
        const float* s = (const float*)enc + i;
        float4 v0 = *(const float4*)s, v1 = *(const float4*)(s + 4);
        union { uint4 u; unsigned short h[8]; } o;
        o.h[0]=f2bf(v0.x); o.h[1]=f2bf(v0.y); o.h[2]=f2bf(v0.z); o.h[3]=f2bf(v0.w);
        o.h[4]=f2bf(v1.x); o.h[5]=f2bf(v1.y); o.h[6]=f2bf(v1.z); o.h[7]=f2bf(v1.w);
        *(uint4*)(dst + i) = o.u;
    } else {
        *(uint4*)(dst + i) = *(const uint4*)((const unsigned short*)enc + i);
    }
}
__global__ void enc_bf_kernel(const void* __restrict__ enc, const int* __restrict__ flg,
                              unsigned short* __restrict__ dst) {
    if (*flg) encconv_body<true>(enc, dst); else encconv_body<false>(enc, dst);
}

// ---------------- weight swizzle: W[K x N] -> bf16 [nt][kc][lane][8] ----------------
template <bool F>
__device__ __forceinline__ void conv_swz_body(const void* W, int K, int Norig,
                                              unsigned short* dst, int permMode, int nChunks) {
    int chunk = blockIdx.x * 4 + (threadIdx.x >> 6);
    if (chunk >= nChunks) return;
    int lane = threadIdx.x & 63;
    int KC = K >> 5;
    int nt = chunk / KC, kc = chunk % KC;
    int quad = lane >> 4, l15 = lane & 15;
    int np = nt * 16 + l15;
    int col;
    if (permMode == 1) col = ((np >> 4) & 3) * 512 + (np >> 6) * 16 + (np & 15);
    else col = np;
    union { s8bf v; unsigned short s[8]; } o;
    if (np < Norig || permMode == 1) {
        size_t base = (size_t)(kc * 32 + quad * 8) * Norig + col;
#pragma unroll
        for (int j = 0; j < 8; ++j) o.s[j] = ldbf<F>(W, base + (size_t)j * Norig);
    } else {
#pragma unroll
        for (int j = 0; j < 8; ++j) o.s[j] = 0;
    }
    *(s8bf*)(dst + ((size_t)chunk * 64 + lane) * 8) = o.v;
}
__global__ void conv_swz_kernel(const int* __restrict__ flg, const void* __restrict__ W,
                                int K, int Norig, unsigned short* __restrict__ dst,
                                int permMode, int nChunks) {
    if (*flg) conv_swz_body<true>(W, K, Norig, dst, permMode, nChunks);
    else      conv_swz_body<false>(W, K, Norig, dst, permMode, nChunks);
}

// ---------------- bias prep (all epilogue biases as f32) ----------------
template <bool F>
__device__ __forceinline__ void conv_bias_body(const void* dab, const void* fbb,
                                               const void* bih, const void* bhh, const void* fcb,
                                               const void* ihb, const void* icb, const void* eab,
                                               float* ag_b, float* g_b, float* fc_b,
                                               float* ihb_f, float* icb_f, float* eab_f) {
    int i = blockIdx.x * 256 + threadIdx.x;
    if (i < 2560) ag_b[i] = (i < 512) ? ldw<F>(dab, i) : ldw<F>(fbb, i - 512);
    else if (i < 2560 + 2048) {
        int np = i - 2560;
        int orig = ((np >> 4) & 3) * 512 + (np >> 6) * 16 + (np & 15);
        g_b[np] = ldw<F>(bih, orig) + ldw<F>(bhh, orig);
    } else if (i < 2560 + 2048 + 20000) fc_b[i - 4608] = ldw<F>(fcb, i - 4608);
    else if (i < 2560 + 2048 + 20000 + 512) ihb_f[i - 24608] = ldw<F>(ihb, i - 24608);
    else if (i < 2560 + 2048 + 20000 + 1024) icb_f[i - 25120] = ldw<F>(icb, i - 25120);
    else if (i < 2560 + 2048 + 20000 + 1536) eab_f[i - 25632] = ldw<F>(eab, i - 25632);
}
__global__ void conv_bias_kernel(const int* __restrict__ flg,
                                 const void* dab, const void* fbb, const void* bih, const void* bhh,
                                 const void* fcb, const void* ihb, const void* icb, const void* eab,
                                 float* ag_b, float* g_b, float* fc_b,
                                 float* ihb_f, float* icb_f, float* eab_f) {
    if (*flg) conv_bias_body<true>(dab, fbb, bih, bhh, fcb, ihb, icb, eab, ag_b, g_b, fc_b, ihb_f, icb_f, eab_f);
    else      conv_bias_body<false>(dab, fbb, bih, bhh, fcb, ihb, icb, eab, ag_b, g_b, fc_b, ihb_f, icb_f, eab_f);
}

// ---------------- mean over P -> bf16 ----------------
template <bool F>
__device__ __forceinline__ void mean_body(const void* enc, unsigned short* mean_bf) {
    int b = blockIdx.x;
    int e = blockIdx.y * 256 + threadIdx.x;
    size_t base = (size_t)b * PP * ENC + e;
    float s = 0.f;
#pragma unroll 4
    for (int p = 0; p < PP; ++p) s += ldw<F>(enc, base + (size_t)p * ENC);
    mean_bf[b * ENC + e] = f2bf(s * (1.0f / (float)PP));
}
__global__ void dec_mean_kernel(const void* __restrict__ enc, const int* __restrict__ flg,
                                unsigned short* __restrict__ mean_bf) {
    if (*flg) mean_body<true>(enc, mean_bf); else mean_body<false>(enc, mean_bf);
}

// ---------------- unified M=64 MFMA GEMM, swizzled-B, fused epilogues ----------------
// epi 0: outF[m*N+n] = v                   (c0)
// epi 1: n<512 -> att2f[m*512+n]=v ; else gatef[m*2048+n-512]=sigmoid(v)
// epi 2: BATCHED preds via LDS transpose -> full-line coalesced stores
// epi 3: hb[m*512+n] = bf16(v)             (h0)
// epi 4: gates (16-wide perm cols) + fused LSTM: c update, hb=h_out (ping-pong), h_all[t]
__global__ __launch_bounds__(256)
void gemm_u_kernel(const int* __restrict__ flg,
                   const unsigned short* __restrict__ A1, int K1, const unsigned short* __restrict__ W1,
                   const unsigned short* __restrict__ A2, int K2, const unsigned short* __restrict__ W2,
                   const float* __restrict__ bias, int N, int epi, int nct,
                   float* __restrict__ outF, float* __restrict__ outF2,
                   unsigned short* __restrict__ hb, float* __restrict__ cptr,
                   unsigned short* __restrict__ h_all,
                   void* __restrict__ outV, const int* __restrict__ lengths, int t) {
    __shared__ float s_g[64 * 132];                 // 33.8 KB; epi4 uses stride-17 view, epi2 stride-132
    int tid = threadIdx.x;
    int wave = tid >> 6, lane = tid & 63;
    int l15 = lane & 15, quad = lane >> 4;
    const unsigned short* Abase1 = A1;
    if (epi == 2) Abase1 = A1 + (size_t)blockIdx.x * 64 * K1;   // t-th M-tile of h_all
    f4acc acc[4][2];
#pragma unroll
    for (int a = 0; a < 4; ++a) { acc[a][0] = (f4acc)0.f; acc[a][1] = (f4acc)0.f; }
#pragma unroll
    for (int pass = 0; pass < 2; ++pass) {
        const unsigned short* A = pass ? A2 : Abase1;
        if (!A) continue;
        int K = pass ? K2 : K1;
        const unsigned short* W = pass ? W2 : W1;
        int KC = K >> 5;
        for (int kc = 0; kc < KC; ++kc) {
            s8bf af[4];
#pragma unroll
            for (int rt = 0; rt < 4; ++rt)
                af[rt] = *(const s8bf*)(A + (size_t)(rt * 16 + l15) * K + kc * 32 + quad * 8);
#pragma unroll
            for (int ct = 0; ct < 2; ++ct) if (ct < nct) {
                int nt = blockIdx.y * 4 * nct + ct * 4 + wave;
                s8bf bv = *(const s8bf*)(W + ((size_t)(nt * KC + kc) * 64 + lane) * 8);
#pragma unroll
                for (int rt = 0; rt < 4; ++rt)
                    acc[rt][ct] = __builtin_amdgcn_mfma_f32_16x16x32_bf16(af[rt], bv, acc[rt][ct], 0, 0, 0);
            }
        }
    }
    if (epi == 4) {
        // nct==1: block covers cols np = blockIdx.y*64 + nl, nl = wave*16+l15
        int nl = wave * 16 + l15;
        int g = (nl >> 4) & 3, dl = nl & 15;
        float bv = bias[blockIdx.y * 64 + nl];
#pragma unroll
        for (int rt = 0; rt < 4; ++rt)
#pragma unroll
            for (int r = 0; r < 4; ++r) {
                int m = rt * 16 + quad * 4 + r;
                s_g[(g * 64 + m) * 17 + dl] = acc[rt][0][r] + bv;
            }
        __syncthreads();
        int m = tid >> 2;
        bool act = t < (lengths[m] - 1);
#pragma unroll
        for (int i = 0; i < 4; ++i) {
            int dl2 = (tid & 3) * 4 + i;
            int d = blockIdx.y * 16 + dl2;
            unsigned short hv;
            if (act) {
                float ig = sigmoidf(s_g[(0 * 64 + m) * 17 + dl2]);
                float fg = sigmoidf(s_g[(1 * 64 + m) * 17 + dl2]);
                float gg = tanhf(s_g[(2 * 64 + m) * 17 + dl2]);
                float og = sigmoidf(s_g[(3 * 64 + m) * 17 + dl2]);
                float cn = fg * cptr[m * DD + d] + ig * gg;
                float hn = og * tanhf(cn);
                cptr[m * DD + d] = cn;
                hv = f2bf(hn);
            } else {
                hv = A2[(size_t)m * K2 + d];     // carry old h forward (ping-pong copy)
            }
            hb[m * DD + d] = hv;
            h_all[((size_t)t * BB + m) * DD + d] = hv;
        }
        return;
    }
    if (epi == 2) {
        // stash biased acc into LDS [m][132], then write full rows coalesced
        int t2 = blockIdx.x;
        int base_n = blockIdx.y * 128;
#pragma unroll
        for (int ct = 0; ct < 2; ++ct) {
            int nl = ct * 64 + wave * 16 + l15;
            int nn = base_n + nl;
            float bv = (nn < VV) ? bias[nn] : 0.f;
#pragma unroll
            for (int rt = 0; rt < 4; ++rt)
#pragma unroll
                for (int r = 0; r < 4; ++r) {
                    int m = rt * 16 + quad * 4 + r;
                    s_g[m * 132 + nl] = acc[rt][ct][r] + bv;
                }
        }
        __syncthreads();
        bool f32o = (*flg != 0);
#pragma unroll
        for (int pass = 0; pass < 8; ++pass) {
            int m = pass * 8 + (tid >> 5);
            int j = tid & 31;                   // float4 index within the 128-col row
            int n = base_n + j * 4;
            if (n < VV) {
                bool act = t2 < (lengths[m] - 1);
                float4 v = *(const float4*)&s_g[m * 132 + j * 4];
                if (!act) { v.x = 0.f; v.y = 0.f; v.z = 0.f; v.w = 0.f; }
                size_t oi = ((size_t)m * TT + t2) * VV + n;
                if (f32o) {
                    *(float4*)((float*)outV + oi) = v;
                } else {
                    uint2 pk;
                    pk.x = (unsigned int)f2bf(v.x) | ((unsigned int)f2bf(v.y) << 16);
                    pk.y = (unsigned int)f2bf(v.z) | ((unsigned int)f2bf(v.w) << 16);
                    *(uint2*)((unsigned short*)outV + oi) = pk;
                }
            }
        }
        return;
    }
#pragma unroll
    for (int ct = 0; ct < 2; ++ct) if (ct < nct) {
        int n = blockIdx.y * 64 * nct + ct * 64 + wave * 16 + l15;
        if (n >= N) continue;
        float bv = bias ? bias[n] : 0.f;
#pragma unroll
        for (int rt = 0; rt < 4; ++rt)
#pragma unroll
            for (int r = 0; r < 4; ++r) {
                int m = rt * 16 + quad * 4 + r;
                float v = acc[rt][ct][r] + bv;
                if (epi == 0)      outF[(size_t)m * N + n] = v;
                else if (epi == 1) {
                    if (n < 512) outF[(size_t)m * 512 + n] = v;
                    else         outF2[(size_t)m * 2048 + (n - 512)] = sigmoidf(v);
                } else if (epi == 3) hb[(size_t)m * DD + n] = f2bf(v);
            }
    }
}

// ---------------- att1: MFMA GEMM (M=12544, N=512, K=2048), swizzled B -> bf16 out ----------------
template <bool F>
__device__ __forceinline__ void att1_gemm_body(const void* enc, const unsigned short* Wsw,
                                               const float* bias, unsigned short* att1) {
    __shared__ __attribute__((aligned(16))) unsigned short As[64 * 40];
    int tid = threadIdx.x;
    int wave = tid >> 6, lane = tid & 63;
    int l15 = lane & 15, quad = lane >> 4;
    int row0 = blockIdx.x * 64;
    f4acc acc[4][2];
#pragma unroll
    for (int a = 0; a < 4; ++a) { acc[a][0] = (f4acc)0.f; acc[a][1] = (f4acc)0.f; }
    int lr = tid >> 2, lk = (tid & 3) * 8;
    for (int kc = 0; kc < 64; ++kc) {
        int k0 = kc * 32;
        if (F) {
            const float* src = (const float*)enc + (size_t)(row0 + lr) * ENC + k0 + lk;
            float4 v0 = *(const float4*)src, v1 = *(const float4*)(src + 4);
            union { s8bf v; unsigned short s[8]; } t8;
            t8.s[0]=f2bf(v0.x); t8.s[1]=f2bf(v0.y); t8.s[2]=f2bf(v0.z); t8.s[3]=f2bf(v0.w);
            t8.s[4]=f2bf(v1.x); t8.s[5]=f2bf(v1.y); t8.s[6]=f2bf(v1.z); t8.s[7]=f2bf(v1.w);
            *(s8bf*)&As[lr * 40 + lk] = t8.v;
        } else {
            *(s8bf*)&As[lr * 40 + lk] =
                *(const s8bf*)((const unsigned short*)enc + (size_t)(row0 + lr) * ENC + k0 + lk);
        }
        __syncthreads();
        s8bf af[4];
#pragma unroll
        for (int rt = 0; rt < 4; ++rt)
            af[rt] = *(const s8bf*)&As[(rt * 16 + l15) * 40 + quad * 8];
#pragma unroll
        for (int ct = 0; ct < 2; ++ct) {
            int nt = blockIdx.y * 8 + ct * 4 + wave;
            s8bf bv = *(const s8bf*)(Wsw + ((size_t)(nt * 64 + kc) * 64 + lane) * 8);
#pragma unroll
            for (int rt = 0; rt < 4; ++rt)
                acc[rt][ct] = __builtin_amdgcn_mfma_f32_16x16x32_bf16(af[rt], bv, acc[rt][ct], 0, 0, 0);
        }
        __syncthreads();
    }
#pragma unroll
    for (int ct = 0; ct < 2; ++ct) {
        int n = blockIdx.y * 128 + ct * 64 + wave * 16 + l15;
        float bv = bias[n];
#pragma unroll
        for (int rt = 0; rt < 4; ++rt)
#pragma unroll
            for (int r = 0; r < 4; ++r) {
                int m = row0 + rt * 16 + quad * 4 + r;
                att1[(size_t)m * AA + n] = f2bf(acc[rt][ct][r] + bv);
            }
    }
}
__global__ __launch_bounds__(256)
void gemm_att1_kernel(const void* __restrict__ enc, const int* __restrict__ flg,
                      const unsigned short* __restrict__ Wsw, const float* __restrict__ bias,
                      unsigned short* __restrict__ att1) {
    if (*flg) att1_gemm_body<true>(enc, Wsw, bias, att1);
    else      att1_gemm_body<false>(enc, Wsw, bias, att1);
}

// ---------------- scores + softmax (16 waves, wave-per-row, bf16 att1) ----------------
template <bool F>
__device__ __forceinline__ void att_body(const unsigned short* att1, const float* att2,
                                         const void* faw, const void* fab,
                                         const int* lengths, float* alpha_ws, void* out, int t) {
    __shared__ float s_sc[256];
    __shared__ float s_red[256];
    int b = blockIdx.x, tid = threadIdx.x;
    int wave = tid >> 6, lane = tid & 63;
    int a0i = lane * 8;
    float4 a2a = *(const float4*)(att2 + (size_t)b * AA + a0i);
    float4 a2b = *(const float4*)(att2 + (size_t)b * AA + a0i + 4);
    float4 w0 = ld4<F>(faw, a0i);
    float4 w1 = ld4<F>(faw, a0i + 4);
    float fabv = ldw<F>(fab, 0);
    if (tid < 256) s_sc[tid] = -1e30f;
    __syncthreads();
    for (int r = wave; r < PP; r += 16) {
        uint4 u = *(const uint4*)(att1 + ((size_t)b * PP + r) * AA + a0i);
        float v0, v1, v2, v3, v4, v5, v6, v7;
        unpack2(u.x, v0, v1); unpack2(u.y, v2, v3);
        unpack2(u.z, v4, v5); unpack2(u.w, v6, v7);
        float acc = fmaxf(v0 + a2a.x, 0.f) * w0.x
                  + fmaxf(v1 + a2a.y, 0.f) * w0.y
                  + fmaxf(v2 + a2a.z, 0.f) * w0.z
                  + fmaxf(v3 + a2a.w, 0.f) * w0.w
                  + fmaxf(v4 + a2b.x, 0.f) * w1.x
                  + fmaxf(v5 + a2b.y, 0.f) * w1.y
                  + fmaxf(v6 + a2b.z, 0.f) * w1.z
                  + fmaxf(v7 + a2b.w, 0.f) * w1.w;
#pragma unroll
        for (int off = 32; off; off >>= 1) acc += __shfl_xor(acc, off, 64);
        if (lane == 0) s_sc[r] = acc + fabv;
    }
    __syncthreads();
    float sc = (tid < 256) ? s_sc[tid] : -1e30f;
    if (tid < 256) s_red[tid] = sc;
    __syncthreads();
    for (int s = 128; s > 0; s >>= 1) { if (tid < s) s_red[tid] = fmaxf(s_red[tid], s_red[tid + s]); __syncthreads(); }
    float m = s_red[0];
    __syncthreads();
    float e = 0.f;
    if (tid < PP) e = __expf(sc - m);
    if (tid < 256) s_red[tid] = e;
    __syncthreads();
    for (int s = 128; s > 0; s >>= 1) { if (tid < s) s_red[tid] += s_red[tid + s]; __syncthreads(); }
    float inv = 1.0f / s_red[0];
    if (tid < PP) {
        float al = e * inv;
        alpha_ws[b * PP + tid] = al;
        bool active = t < (lengths[b] - 1);
        st1<F>(out, PRED_ELEMS + (size_t)(b * TT + t) * PP + tid, active ? al : 0.f);
    }
}
__global__ __launch_bounds__(1024)
void dec_att_kernel(const unsigned short* __restrict__ att1, const float* __restrict__ att2,
                    const int* __restrict__ flg,
                    const void* __restrict__ faw, const void* __restrict__ fab,
                    const int* __restrict__ lengths,
                    float* __restrict__ alpha_ws, void* __restrict__ out, int t) {
    if (*flg) att_body<true>(att1, att2, faw, fab, lengths, alpha_ws, out, t);
    else      att_body<false>(att1, att2, faw, fab, lengths, alpha_ws, out, t);
}

// ---------------- fused context + gate + x_bf assembly ----------------
// grid (BB, 4), 256 thr; block (b,yc) handles 512 ctx dims; yc==0 also writes emb part
// forceBf=1: encp is the bf16 workspace copy. forceBf=0: encp is the raw input (dtype via *flg).
template <bool F>
__device__ __forceinline__ void ctx_body(const void* encp, const float* alpha_ws,
                                         const float* gate, const void* emb, const int* captions,
                                         unsigned short* x_bf, int t) {
    __shared__ float s_al[PP];
    int b = blockIdx.x, yc = blockIdx.y, tid = threadIdx.x;
    if (tid < PP) s_al[tid] = alpha_ws[b * PP + tid];
    __syncthreads();
    if (yc == 0) {
        int cap = captions[b * ML + t];
        int i = tid * 2;
        float2 ev = ld2<F>(emb, (size_t)cap * EE + i);
        *(unsigned int*)(x_bf + (size_t)b * 2560 + i) =
            (unsigned int)f2bf(ev.x) | ((unsigned int)f2bf(ev.y) << 16);
    }
    int e = yc * 512 + tid * 2;
    float a0 = 0.f, a1 = 0.f;
    size_t base = (size_t)b * PP * ENC + e;
#pragma unroll 4
    for (int p = 0; p < PP; ++p) {
        float al = s_al[p];
        float2 v = ld2<F>(encp, base + (size_t)p * ENC);
        a0 += al * v.x; a1 += al * v.y;
    }
    float2 g = *(const float2*)&gate[(size_t)b * ENC + e];
    *(unsigned int*)(x_bf + (size_t)b * 2560 + EE + e) =
        (unsigned int)f2bf(a0 * g.x) | ((unsigned int)f2bf(a1 * g.y) << 16);
}
// emb dtype always follows *flg; enc read is bf16 when forceBf, else follows *flg.
template <bool FEMB>
__device__ __forceinline__ void ctx_sel(const void* encp, int forceBf, const float* alpha_ws,
                                        const float* gate, const void* emb, const int* captions,
                                        unsigned short* x_bf, int t);
__global__ void dec_ctx_kernel(const void* __restrict__ encp, const int* __restrict__ flg, int forceBf,
                               const float* __restrict__ alpha_ws, const float* __restrict__ gate,
                               const void* __restrict__ emb, const int* __restrict__ captions,
                               unsigned short* __restrict__ x_bf, int t) {
    __shared__ float s_al[PP];
    int b = blockIdx.x, yc = blockIdx.y, tid = threadIdx.x;
    if (tid < PP) s_al[tid] = alpha_ws[b * PP + tid];
    __syncthreads();
    bool f32in = (*flg != 0);
    if (yc == 0) {
        int cap = captions[b * ML + t];
        int i = tid * 2;
        float2 ev = f32in ? ld2<true>(emb, (size_t)cap * EE + i) : ld2<false>(emb, (size_t)cap * EE + i);
        *(unsigned int*)(x_bf + (size_t)b * 2560 + i) =
            (unsigned int)f2bf(ev.x) | ((unsigned int)f2bf(ev.y) << 16);
    }
    int e = yc * 512 + tid * 2;
    float a0 = 0.f, a1 = 0.f;
    size_t base = (size_t)b * PP * ENC + e;
    bool encF32 = f32in && !forceBf;
    if (encF32) {
#pragma unroll 4
        for (int p = 0; p < PP; ++p) {
            float al = s_al[p];
            float2 v = *(const float2*)((const float*)encp + base + (size_t)p * ENC);
            a0 += al * v.x; a1 += al * v.y;
        }
    } else {
#pragma unroll 4
        for (int p = 0; p < PP; ++p) {
            float al = s_al[p];
            unsigned int u = *(const unsigned int*)((const unsigned short*)encp + base + (size_t)p * ENC);
            float lo, hi; unpack2(u, lo, hi);
            a0 += al * lo; a1 += al * hi;
        }
    }
    float2 g = *(const float2*)&gate[(size_t)b * ENC + e];
    *(unsigned int*)(x_bf + (size_t)b * 2560 + EE + e) =
        (unsigned int)f2bf(a0 * g.x) | ((unsigned int)f2bf(a1 * g.y) << 16);
}

extern "C" void kernel_launch(void* const* d_in, const int* in_sizes, int n_in,
                              void* d_out, int out_size, void* d_ws, size_t ws_size,
                              hipStream_t stream) {
    const void* enc      = d_in[0];
    const int* captions  = (const int*)d_in[1];
    const int* lengths   = (const int*)d_in[2];
    const void* emb      = d_in[3];
    const void* eaw      = d_in[4];
    const void* eab      = d_in[5];
    const void* daw      = d_in[6];
    const void* dab      = d_in[7];
    const void* faw      = d_in[8];
    const void* fab      = d_in[9];
    const void* wih      = d_in[10];
    const void* bih      = d_in[11];
    const void* whh      = d_in[12];
    const void* bhh      = d_in[13];
    const void* ihw      = d_in[14];
    const void* ihb      = d_in[15];
    const void* icw      = d_in[16];
    const void* icb      = d_in[17];
    const void* fbw      = d_in[18];
    const void* fbb      = d_in[19];
    const void* fcw      = d_in[20];
    const void* fcb      = d_in[21];

    char* cur = (char*)d_ws;
    auto alloc = [&](size_t bytes) { void* p = cur; cur += (bytes + 255) & ~(size_t)255; return p; };
    int* flg               = (int*)alloc(4);
    unsigned short* h_bufA = (unsigned short*)alloc((size_t)BB * DD * 2);
    unsigned short* h_bufB = (unsigned short*)alloc((size_t)BB * DD * 2);
    unsigned short* h_all  = (unsigned short*)alloc((size_t)TT * BB * DD * 2);   // 1.4 MB
    unsigned short* x_bf   = (unsigned short*)alloc((size_t)BB * 2560 * 2);
    unsigned short* mean_bf= (unsigned short*)alloc((size_t)BB * ENC * 2);
    float* c               = (float*)alloc((size_t)BB * DD * 4);
    float* att2            = (float*)alloc((size_t)BB * AA * 4);
    float* gate            = (float*)alloc((size_t)BB * ENC * 4);
    float* alpha           = (float*)alloc((size_t)BB * PP * 4);
    float* ag_bias         = (float*)alloc(2560 * 4);
    float* g_bias          = (float*)alloc(2048 * 4);
    float* fc_bias         = (float*)alloc(20000 * 4);
    float* ihb_f           = (float*)alloc(512 * 4);
    float* icb_f           = (float*)alloc(512 * 4);
    float* eab_f           = (float*)alloc(512 * 4);
    unsigned short* eaw_sw = (unsigned short*)alloc((size_t)32 * 64 * 512 * 2);       // 2.1 MB
    unsigned short* ag_sw  = (unsigned short*)alloc((size_t)160 * 16 * 512 * 2);      // 2.6 MB
    unsigned short* ihw_sw = (unsigned short*)alloc((size_t)32 * 64 * 512 * 2);
    unsigned short* icw_sw = (unsigned short*)alloc((size_t)32 * 64 * 512 * 2);
    unsigned short* wih_sw = (unsigned short*)alloc((size_t)128 * 80 * 512 * 2);      // 10.5 MB
    unsigned short* whh_sw = (unsigned short*)alloc((size_t)128 * 16 * 512 * 2);      // 2.1 MB
    unsigned short* fcw_sw = (unsigned short*)alloc((size_t)1256 * 16 * 512 * 2);     // 20.6 MB
    unsigned short* att1_bf= (unsigned short*)alloc((size_t)BB * PP * AA * 2);        // 12.9 MB
    // enc_bf only if workspace is big enough; otherwise fall back to reading raw enc.
    size_t enc_bf_bytes = (size_t)BB * PP * ENC * 2;                                  // 51.4 MB
    size_t used = (size_t)(cur - (char*)d_ws);
    bool have_enc_bf = (used + enc_bf_bytes + 256 <= ws_size);
    unsigned short* enc_bf = have_enc_bf ? (unsigned short*)alloc(enc_bf_bytes) : nullptr;

    dec_detect_kernel<<<1, 256, 0, stream>>>((const unsigned short*)enc, flg);
    if (have_enc_bf)
        enc_bf_kernel<<<(BB * PP * ENC) / (256 * 8), 256, 0, stream>>>(enc, flg, enc_bf);
    conv_swz_kernel<<<(32 * 64 + 3) / 4, 256, 0, stream>>>(flg, eaw, ENC, AA, eaw_sw, 0, 32 * 64);
    conv_swz_kernel<<<(32 * 16 + 3) / 4, 256, 0, stream>>>(flg, daw, DD, AA, ag_sw, 0, 32 * 16);
    conv_swz_kernel<<<(128 * 16 + 3) / 4, 256, 0, stream>>>(flg, fbw, DD, ENC, ag_sw + (size_t)32 * 16 * 512, 0, 128 * 16);
    conv_swz_kernel<<<(32 * 64 + 3) / 4, 256, 0, stream>>>(flg, ihw, ENC, DD, ihw_sw, 0, 32 * 64);
    conv_swz_kernel<<<(32 * 64 + 3) / 4, 256, 0, stream>>>(flg, icw, ENC, DD, icw_sw, 0, 32 * 64);
    conv_swz_kernel<<<(128 * 80 + 3) / 4, 256, 0, stream>>>(flg, wih, 2560, 2048, wih_sw, 1, 128 * 80);
    conv_swz_kernel<<<(128 * 16 + 3) / 4, 256, 0, stream>>>(flg, whh, DD, 2048, whh_sw, 1, 128 * 16);
    conv_swz_kernel<<<(1256 * 16 + 3) / 4, 256, 0, stream>>>(flg, fcw, DD, VV, fcw_sw, 0, 1256 * 16);
    conv_bias_kernel<<<(26144 + 255) / 256, 256, 0, stream>>>(flg, dab, fbb, bih, bhh, fcb, ihb, icb, eab,
                                                              ag_bias, g_bias, fc_bias, ihb_f, icb_f, eab_f);
    dec_mean_kernel<<<dim3(BB, ENC / 256), 256, 0, stream>>>(enc, flg, mean_bf);
    // h0, c0 via MFMA
    gemm_u_kernel<<<dim3(1, 4), 256, 0, stream>>>(flg, mean_bf, ENC, ihw_sw, nullptr, 0, nullptr,
                                                  ihb_f, DD, 3, 2, nullptr, nullptr, h_bufA, nullptr,
                                                  nullptr, nullptr, nullptr, 0);
    gemm_u_kernel<<<dim3(1, 4), 256, 0, stream>>>(flg, mean_bf, ENC, icw_sw, nullptr, 0, nullptr,
                                                  icb_f, DD, 0, 2, c, nullptr, nullptr, nullptr,
                                                  nullptr, nullptr, nullptr, 0);
    gemm_att1_kernel<<<dim3(196, 4), 256, 0, stream>>>(enc, flg, eaw_sw, eab_f, att1_bf);

    const void* ctx_enc = have_enc_bf ? (const void*)enc_bf : enc;
    int forceBf = have_enc_bf ? 1 : 0;
    unsigned short* hcur = h_bufA;
    for (int t = 0; t < TT; ++t) {
        unsigned short* hnext = (hcur == h_bufA) ? h_bufB : h_bufA;
        // att2 (cols 0..511) + f_beta gate (cols 512..2559), fused; nct=1 -> 40 blocks
        gemm_u_kernel<<<dim3(1, 40), 256, 0, stream>>>(flg, hcur, DD, ag_sw, nullptr, 0, nullptr,
                                                       ag_bias, 2560, 1, 1, att2, gate, nullptr, nullptr,
                                                       nullptr, nullptr, nullptr, 0);
        dec_att_kernel<<<BB, 1024, 0, stream>>>(att1_bf, att2, flg, faw, fab, lengths, alpha, d_out, t);
        dec_ctx_kernel<<<dim3(BB, 4), 256, 0, stream>>>(ctx_enc, flg, forceBf, alpha, gate, emb, captions, x_bf, t);
        // gates GEMM + fused LSTM pointwise (16-wide gate-interleaved cols); nct=1 -> 32 blocks
        gemm_u_kernel<<<dim3(1, 32), 256, 0, stream>>>(flg, x_bf, 2560, wih_sw, hcur, DD, whh_sw,
                                                       g_bias, 2048, 4, 1, nullptr, nullptr, hnext, c,
                                                       h_all, nullptr, lengths, t);
        hcur = hnext;
    }
    // batched vocab projection: M = TT*64, grid (t, n-tile) -> 3297 blocks
    gemm_u_kernel<<<dim3(TT, 157), 256, 0, stream>>>(flg, h_all, DD, fcw_sw, nullptr, 0, nullptr,
                                                     fc_bias, VV, 2, 2, nullptr, nullptr, nullptr, nullptr,
                                                     nullptr, d_out, lengths, 0);
}